// Round 7
// baseline (243.198 us; speedup 1.0000x reference)
//
#include <hip/hip_runtime.h>
#include <cstdint>

#define HW  128
#define NCH 256
#define NOC 18      // G*K*K
#define PLANE (HW * HW)
#define EPSBN 1e-5f

typedef __attribute__((ext_vector_type(8)))  short bf16x8;
typedef __attribute__((ext_vector_type(16))) float f32x16;

__device__ __forceinline__ unsigned short f2bf(float f) {
    union { float f; uint32_t u; } c; c.f = f;
    uint32_t u = c.u;
    uint32_t r = u + 0x7FFFu + ((u >> 16) & 1u);   // RNE
    return (unsigned short)(r >> 16);
}

// LDS tile [slot(4)][px(66)][ic(64)] bf16, px stride 128 B.
// XOR px low bits into the 16B-granule index so a wave's b128 reads at
// consecutive px spread over all 32 banks (write side uses same involution).
__device__ __forceinline__ int lds_off(int slot, int px, int ic) {
    int b = ((slot * 66 + px) * 64 + ic) * 2;
    return b ^ ((px & 7) << 4);
}

__device__ __forceinline__ int4 pack8(const float* v) {
    int4 d;
    d.x = (uint32_t)f2bf(v[0]) | ((uint32_t)f2bf(v[1]) << 16);
    d.y = (uint32_t)f2bf(v[2]) | ((uint32_t)f2bf(v[3]) << 16);
    d.z = (uint32_t)f2bf(v[4]) | ((uint32_t)f2bf(v[5]) << 16);
    d.w = (uint32_t)f2bf(v[6]) | ((uint32_t)f2bf(v[7]) << 16);
    return d;
}

// ------------- Kernel W: pack weights -> wB[tap][ic>>3][oc(32 pad)][ic&7] bf16
__global__ __launch_bounds__(256) void pasa_wprep(
    const float* __restrict__ w, unsigned short* __restrict__ wB)
{
    int idx = blockIdx.x * 256 + threadIdx.x;      // 9*32*32*8 = 73728
    int icl = idx & 7;
    int oc  = (idx >> 3) & 31;
    int icb = (idx >> 8) & 31;
    int tap = idx >> 13;
    int ic  = icb * 8 + icl;
    float v = (oc < NOC) ? w[((size_t)oc * NCH + ic) * 9 + tap] : 0.0f;
    wB[idx] = f2bf(v);
}

// ------------- Kernel A: implicit-GEMM conv + BN + softmax (fused) ---------
// grid 1024 (n x ypair x pxhalf), 256 thr = 4 waves. Each wave stages one
// row (66 px x 64 ic per chunk) and computes one C tile [oc32 x px32].
// 4 blocks/CU; reg-prefetch of next chunk hides global latency under MFMA.
__global__ __launch_bounds__(256, 4) void pasa_conv_mfma(
    const float* __restrict__ x, const unsigned short* __restrict__ wB,
    const float* __restrict__ gamma, const float* __restrict__ beta,
    const float* __restrict__ rmean, const float* __restrict__ rvar,
    float* __restrict__ sigma)
{
    __shared__ __align__(16) char lds[4 * 66 * 64 * 2];   // 33792 B

    int flat = blockIdx.x;                 // [0,1024)
    int nf   = (flat & 7) * 128 + (flat >> 3);  // XCD owns one image
    const int n   = nf >> 7;
    const int rem = nf & 127;
    const int y0  = (rem >> 1) * 2;        // output row pair
    const int P0  = (rem & 1) * 64;        // px half

    const int tid  = threadIdx.x;
    const int lane = tid & 63;
    const int wv   = tid >> 6;             // wave 0..3 (also staging row)
    const int m    = lane & 31;            // MFMA col (pixel in tile)
    const int hi   = lane >> 5;            // k-half selector

    int grow;                              // staged row (reflect)
    if      (wv == 0) grow = (y0 == 0) ? 1 : y0 - 1;
    else if (wv == 1) grow = y0;
    else if (wv == 2) grow = y0 + 1;
    else              grow = (y0 + 1 == HW - 1) ? HW - 2 : y0 + 2;

    const float* xrow  = x + (size_t)n * NCH * PLANE + (size_t)grow * HW;
    const float* gmain = xrow + P0 + lane;          // this lane's main px
    const int hx0 = (P0 == 0)  ? 1   : P0 - 1;      // left halo px (reflect)
    const int hx1 = (P0 == 64) ? 126 : P0 + 64;     // right halo px (reflect)

    const int out_row = wv >> 1;
    const int px_t    = (wv & 1) * 32;

    f32x16 acc;
    #pragma unroll
    for (int i = 0; i < 16; ++i) acc[i] = 0.0f;

    float pre[32];
    // prologue: prefetch chunk 0, ic-batches 0..3
    #pragma unroll
    for (int b = 0; b < 4; ++b)
        #pragma unroll
        for (int i = 0; i < 8; ++i)
            pre[b * 8 + i] = gmain[(size_t)(b * 8 + i) * PLANE];

    for (int chunk = 0; chunk < 4; ++chunk) {
        const int icg0 = chunk * 64;
        // halo columns: lane = ic, 2 uncoalesced loads, issued first
        float h0 = xrow[(size_t)(icg0 + lane) * PLANE + hx0];
        float h1 = xrow[(size_t)(icg0 + lane) * PLANE + hx1];
        // direct ic-batches 4..7
        float dir[32];
        #pragma unroll
        for (int b = 0; b < 4; ++b)
            #pragma unroll
            for (int i = 0; i < 8; ++i)
                dir[b * 8 + i] = gmain[(size_t)(icg0 + 32 + b * 8 + i) * PLANE];
        // write prefetched batches 0..3
        #pragma unroll
        for (int b = 0; b < 4; ++b)
            *(int4*)(lds + lds_off(wv, lane + 1, b * 8)) = pack8(&pre[b * 8]);
        // write direct batches 4..7
        #pragma unroll
        for (int b = 0; b < 4; ++b)
            *(int4*)(lds + lds_off(wv, lane + 1, 32 + b * 8)) = pack8(&dir[b * 8]);
        // write halo columns (2 B per lane, contiguous across lanes)
        *(unsigned short*)(lds + lds_off(wv, 0,  lane)) = f2bf(h0);
        *(unsigned short*)(lds + lds_off(wv, 65, lane)) = f2bf(h1);
        __syncthreads();
        // prefetch next chunk's batches 0..3 (flies under MFMA phase)
        if (chunk < 3) {
            #pragma unroll
            for (int b = 0; b < 4; ++b)
                #pragma unroll
                for (int i = 0; i < 8; ++i)
                    pre[b * 8 + i] = gmain[(size_t)(icg0 + 64 + b * 8 + i) * PLANE];
        }
        // ---- MFMA: 9 taps x 4 k-steps, D = W·X ----
        #pragma unroll
        for (int tap = 0; tap < 9; ++tap) {
            const int dy = tap / 3;
            const int dx = tap % 3 - 1;
            const int slot = out_row + dy;
            const int apx  = px_t + m + 1 + dx;
            #pragma unroll
            for (int ks = 0; ks < 4; ++ks) {
                const int k0 = ks * 16;
                bf16x8 a = *(const bf16x8*)(lds + lds_off(slot, apx, k0 + hi * 8));
                bf16x8 b = *(const bf16x8*)(wB +
                    (((size_t)tap * 32 + ((icg0 + k0) >> 3) + hi) * 32 + m) * 8);
                acc = __builtin_amdgcn_mfma_f32_32x32x16_bf16(b, a, acc, 0, 0, 0);
            }
        }
        __syncthreads();
    }

    // ---- epilogue: BN + softmax over 18 channels, write sigma ----
    // C/D layout: col(px)=lane&31, row(oc)=(r&3)+8*(r>>2)+4*hi
    float vals[16];
    float mx = -3.0e38f;
    #pragma unroll
    for (int r = 0; r < 16; ++r) {
        int oc = (r & 3) + 8 * (r >> 2) + 4 * hi;
        float v = -3.0e38f;
        if (oc < NOC) {
            float sc = gamma[oc] * rsqrtf(rvar[oc] + EPSBN);
            float b  = beta[oc] - rmean[oc] * sc;
            v = fmaf(acc[r], sc, b);
        }
        vals[r] = v;
        mx = fmaxf(mx, v);
    }
    mx = fmaxf(mx, __shfl_xor(mx, 32));
    float s = 0.0f;
    #pragma unroll
    for (int r = 0; r < 16; ++r) {
        int oc = (r & 3) + 8 * (r >> 2) + 4 * hi;
        float e = (oc < NOC) ? __expf(vals[r] - mx) : 0.0f;
        vals[r] = e;
        s += e;
    }
    s += __shfl_xor(s, 32);
    const float inv = 1.0f / s;

    float* so = sigma + (size_t)n * NOC * PLANE
              + (size_t)(y0 + out_row) * HW + P0 + px_t + m;
    #pragma unroll
    for (int r = 0; r < 16; ++r) {
        int oc = (r & 3) + 8 * (r >> 2) + 4 * hi;
        if (oc < NOC) so[(size_t)oc * PLANE] = vals[r] * inv;
    }
}

// ------------- Kernel B: per-pixel dynamic 3x3 pooling ---------------------
// grid: 2048 blocks (n(8) x chsplit(8) x yq(32)); each thread: 16 channels.
__global__ __launch_bounds__(256) void pasa_pool(
    const float* __restrict__ x, const float* __restrict__ sigma,
    float* __restrict__ out)
{
    int flat = blockIdx.x;                 // [0,2048)
    int nf   = (flat & 7) * 256 + (flat >> 3);   // XCD owns one image
    const int n       = nf >> 8;
    const int chsplit = (nf >> 5) & 7;
    const int yq      = nf & 31;

    const int q = threadIdx.x & 31;
    const int r = (threadIdx.x >> 5) & 3;
    const int s = threadIdx.x >> 7;        // group 0/1

    const int y   = yq * 4 + r;
    const int px0 = q * 4;

    const int ym = (y == 0)      ? 1      : y - 1;
    const int yp = (y == HW - 1) ? HW - 2 : y + 1;
    const int lx = (px0 == 0)        ? 1      : px0 - 1;
    const int rx = (px0 + 4 > HW - 1)? HW - 2 : px0 + 4;

    const float* sg = sigma + ((size_t)n * NOC + s * 9) * PLANE
                            + (size_t)y * HW + px0;
    float sgv[9][4];
    #pragma unroll
    for (int k = 0; k < 9; ++k) {
        float4 t = *(const float4*)(sg + (size_t)k * PLANE);
        sgv[k][0] = t.x; sgv[k][1] = t.y; sgv[k][2] = t.z; sgv[k][3] = t.w;
    }

    const int c0 = s * 128 + chsplit * 16;
    const float* xn = x + (size_t)n * NCH * PLANE;
    float*       on = out + (size_t)n * NCH * PLANE;

    for (int cc = 0; cc < 16; ++cc) {
        const int c = c0 + cc;
        const float* xc = xn + (size_t)c * PLANE;
        const float* rws[3] = { xc + (size_t)ym * HW, xc + (size_t)y * HW,
                                xc + (size_t)yp * HW };
        float ov[4] = {0.f, 0.f, 0.f, 0.f};
        #pragma unroll
        for (int dy = 0; dy < 3; ++dy) {
            const float* rr = rws[dy];
            float  w0 = rr[lx];
            float4 mm = *(const float4*)(rr + px0);
            float  w5 = rr[rx];
            float wvv[6] = { w0, mm.x, mm.y, mm.z, mm.w, w5 };
            #pragma unroll
            for (int j = 0; j < 4; ++j) {
                #pragma unroll
                for (int dx = 0; dx < 3; ++dx)
                    ov[j] = fmaf(wvv[j + dx], sgv[dy * 3 + dx][j], ov[j]);
            }
        }
        float4 o4 = { ov[0], ov[1], ov[2], ov[3] };
        *(float4*)(on + (size_t)c * PLANE + (size_t)y * HW + px0) = o4;
    }
}

extern "C" void kernel_launch(void* const* d_in, const int* in_sizes, int n_in,
                              void* d_out, int out_size, void* d_ws, size_t ws_size,
                              hipStream_t stream) {
    const float* x     = (const float*)d_in[0];
    const float* w     = (const float*)d_in[1];
    const float* gamma = (const float*)d_in[2];
    const float* beta  = (const float*)d_in[3];
    const float* rmean = (const float*)d_in[4];
    const float* rvar  = (const float*)d_in[5];
    float* out   = (float*)d_out;
    float* sigma = (float*)d_ws;                 // 8*18*16384*4 = 9.44 MB

    unsigned short* wB = (unsigned short*)((char*)d_out + (size_t)64 * 1024 * 1024);

    pasa_wprep<<<dim3(288), dim3(256), 0, stream>>>(w, wB);
    pasa_conv_mfma<<<dim3(1024), dim3(256), 0, stream>>>(
        x, wB, gamma, beta, rmean, rvar, sigma);
    pasa_pool<<<dim3(2048), dim3(256), 0, stream>>>(x, sigma, out);
}

// Round 8
// 207.900 us; speedup vs baseline: 1.1698x; 1.1698x over previous
//
#include <hip/hip_runtime.h>
#include <cstdint>

#define HW  128
#define NCH 256
#define NOC 18      // G*K*K
#define PLANE (HW * HW)
#define EPSBN 1e-5f

typedef __attribute__((ext_vector_type(8)))  short bf16x8;
typedef __attribute__((ext_vector_type(16))) float f32x16;

__device__ __forceinline__ unsigned short f2bf(float f) {
    union { float f; uint32_t u; } c; c.f = f;
    uint32_t u = c.u;
    uint32_t r = u + 0x7FFFu + ((u >> 16) & 1u);   // RNE
    return (unsigned short)(r >> 16);
}

// ------------- Kernel W: pack weights -> wB[tap][ic>>3][oc(32 pad)][ic&7] bf16
__global__ __launch_bounds__(256) void pasa_wprep(
    const float* __restrict__ w, unsigned short* __restrict__ wB)
{
    int idx = blockIdx.x * 256 + threadIdx.x;      // 9*32*32*8 = 73728
    int icl = idx & 7;
    int oc  = (idx >> 3) & 31;
    int icb = (idx >> 8) & 31;
    int tap = idx >> 13;
    int ic  = icb * 8 + icl;
    float v = (oc < NOC) ? w[((size_t)oc * NCH + ic) * 9 + tap] : 0.0f;
    wB[idx] = f2bf(v);
}

// ------------- Kernel C: x NCHW fp32 -> xc NHWC bf16 -----------------------
// grid 4096 = (n(8) x y(128) x cq(4)); block 256: px=t&127, ch=t>>7.
// Each thread: 32 channels at one (n,y,px). Reads coalesced along px;
// 16B writes; each block completes full 128B lines -> L2 merges.
__global__ __launch_bounds__(256) void pasa_cvt(
    const float* __restrict__ x, unsigned short* __restrict__ xc)
{
    int flat = blockIdx.x;
    const int cq = flat & 3;
    const int y  = (flat >> 2) & 127;
    const int n  = flat >> 9;

    const int px = threadIdx.x & 127;
    const int ch = threadIdx.x >> 7;
    const int c0 = cq * 64 + ch * 32;

    const float* xp = x + ((size_t)n * NCH) * PLANE + (size_t)y * HW + px;
    unsigned short* op = xc + (((size_t)n * HW + y) * HW + px) * NCH + c0;

    #pragma unroll
    for (int cg = 0; cg < 4; ++cg) {
        float v[8];
        #pragma unroll
        for (int j = 0; j < 8; ++j)
            v[j] = xp[(size_t)(c0 + cg * 8 + j) * PLANE];
        int4 d;
        d.x = (uint32_t)f2bf(v[0]) | ((uint32_t)f2bf(v[1]) << 16);
        d.y = (uint32_t)f2bf(v[2]) | ((uint32_t)f2bf(v[3]) << 16);
        d.z = (uint32_t)f2bf(v[4]) | ((uint32_t)f2bf(v[5]) << 16);
        d.w = (uint32_t)f2bf(v[6]) | ((uint32_t)f2bf(v[7]) << 16);
        *(int4*)(op + cg * 8) = d;
    }
}

// ------------- Kernel A: implicit-GEMM conv + BN + softmax -----------------
// Direct-from-global MFMA: no LDS, no barriers. grid 1024 (n x y), 256 thr
// = 4 waves, wave wv owns px tile [wv*32, wv*32+32). C[oc32 x px32] via
// mfma_32x32x16_bf16(W, X, acc); B-frag = 16B contiguous NHWC load.
__global__ __launch_bounds__(256, 4) void pasa_conv_mfma(
    const unsigned short* __restrict__ xc, const unsigned short* __restrict__ wB,
    const float* __restrict__ gamma, const float* __restrict__ beta,
    const float* __restrict__ rmean, const float* __restrict__ rvar,
    float* __restrict__ sigma)
{
    int flat = blockIdx.x;                 // [0,1024)
    int nf   = (flat & 7) * 128 + (flat >> 3);   // XCD owns one image
    const int n = nf >> 7;
    const int y = nf & 127;

    const int lane = threadIdx.x & 63;
    const int wv   = threadIdx.x >> 6;     // px tile
    const int m    = lane & 31;
    const int hi   = lane >> 5;

    const int p0 = wv * 32 + m;
    int pxv[3];
    pxv[0] = (p0 == 0)   ? 1   : p0 - 1;   // reflect
    pxv[1] = p0;
    pxv[2] = (p0 == 127) ? 126 : p0 + 1;

    int gy[3];
    gy[0] = (y == 0)   ? 1   : y - 1;
    gy[1] = y;
    gy[2] = (y == 127) ? 126 : y + 1;

    const char* xn = (const char*)xc + (size_t)n * HW * HW * NCH * 2;
    const char* base[3][3];
    #pragma unroll
    for (int dy = 0; dy < 3; ++dy)
        #pragma unroll
        for (int dx = 0; dx < 3; ++dx)
            base[dy][dx] = xn + (((size_t)gy[dy] * HW + pxv[dx]) * NCH + hi * 8) * 2;

    const char* wb = (const char*)wB;

    f32x16 acc;
    #pragma unroll
    for (int i = 0; i < 16; ++i) acc[i] = 0.0f;

    #pragma unroll
    for (int chunk = 0; chunk < 4; ++chunk) {
        const int co = chunk * 128;        // 64 ic * 2B
        #pragma unroll
        for (int dy = 0; dy < 3; ++dy) {
            #pragma unroll
            for (int dx = 0; dx < 3; ++dx) {
                const int tap = dy * 3 + dx;
                const char* bp = base[dy][dx] + co;
                const char* wp = wb + (((size_t)(tap * 32 + chunk * 8 + hi) * 32 + m) << 4);
                bf16x8 x0 = *(const bf16x8*)(bp);
                bf16x8 w0 = *(const bf16x8*)(wp);
                acc = __builtin_amdgcn_mfma_f32_32x32x16_bf16(w0, x0, acc, 0, 0, 0);
                bf16x8 x1 = *(const bf16x8*)(bp + 32);
                bf16x8 w1 = *(const bf16x8*)(wp + 1024);
                acc = __builtin_amdgcn_mfma_f32_32x32x16_bf16(w1, x1, acc, 0, 0, 0);
                bf16x8 x2 = *(const bf16x8*)(bp + 64);
                bf16x8 w2 = *(const bf16x8*)(wp + 2048);
                acc = __builtin_amdgcn_mfma_f32_32x32x16_bf16(w2, x2, acc, 0, 0, 0);
                bf16x8 x3 = *(const bf16x8*)(bp + 96);
                bf16x8 w3 = *(const bf16x8*)(wp + 3072);
                acc = __builtin_amdgcn_mfma_f32_32x32x16_bf16(w3, x3, acc, 0, 0, 0);
            }
        }
    }

    // ---- epilogue: BN + softmax over 18 channels, write sigma ----
    // C/D layout: col(px)=lane&31, row(oc)=(r&3)+8*(r>>2)+4*hi
    float vals[16];
    float mx = -3.0e38f;
    #pragma unroll
    for (int r = 0; r < 16; ++r) {
        int oc = (r & 3) + 8 * (r >> 2) + 4 * hi;
        float v = -3.0e38f;
        if (oc < NOC) {
            float sc = gamma[oc] * rsqrtf(rvar[oc] + EPSBN);
            float b  = beta[oc] - rmean[oc] * sc;
            v = fmaf(acc[r], sc, b);
        }
        vals[r] = v;
        mx = fmaxf(mx, v);
    }
    mx = fmaxf(mx, __shfl_xor(mx, 32));
    float s = 0.0f;
    #pragma unroll
    for (int r = 0; r < 16; ++r) {
        int oc = (r & 3) + 8 * (r >> 2) + 4 * hi;
        float e = (oc < NOC) ? __expf(vals[r] - mx) : 0.0f;
        vals[r] = e;
        s += e;
    }
    s += __shfl_xor(s, 32);
    const float inv = 1.0f / s;

    float* so = sigma + (size_t)n * NOC * PLANE + (size_t)y * HW + p0;
    #pragma unroll
    for (int r = 0; r < 16; ++r) {
        int oc = (r & 3) + 8 * (r >> 2) + 4 * hi;
        if (oc < NOC) so[(size_t)oc * PLANE] = vals[r] * inv;
    }
}

// ------------- Kernel B: per-pixel dynamic 3x3 pooling (R5 version) --------
// grid: 2048 blocks (n(8) x chsplit(8) x yq(32)); each thread: 16 channels.
__global__ __launch_bounds__(256) void pasa_pool(
    const float* __restrict__ x, const float* __restrict__ sigma,
    float* __restrict__ out)
{
    int flat = blockIdx.x;                 // [0,2048)
    int nf   = (flat & 7) * 256 + (flat >> 3);   // XCD owns one image
    const int n       = nf >> 8;
    const int chsplit = (nf >> 5) & 7;
    const int yq      = nf & 31;

    const int q = threadIdx.x & 31;
    const int r = (threadIdx.x >> 5) & 3;
    const int s = threadIdx.x >> 7;        // group 0/1

    const int y   = yq * 4 + r;
    const int px0 = q * 4;

    const int ym = (y == 0)      ? 1      : y - 1;
    const int yp = (y == HW - 1) ? HW - 2 : y + 1;
    const int lx = (px0 == 0)        ? 1      : px0 - 1;
    const int rx = (px0 + 4 > HW - 1)? HW - 2 : px0 + 4;

    const float* sg = sigma + ((size_t)n * NOC + s * 9) * PLANE
                            + (size_t)y * HW + px0;
    float sgv[9][4];
    #pragma unroll
    for (int k = 0; k < 9; ++k) {
        float4 t = *(const float4*)(sg + (size_t)k * PLANE);
        sgv[k][0] = t.x; sgv[k][1] = t.y; sgv[k][2] = t.z; sgv[k][3] = t.w;
    }

    const int c0 = s * 128 + chsplit * 16;
    const float* xn = x + (size_t)n * NCH * PLANE;
    float*       on = out + (size_t)n * NCH * PLANE;

    for (int cc = 0; cc < 16; ++cc) {
        const int c = c0 + cc;
        const float* xcp = xn + (size_t)c * PLANE;
        const float* rws[3] = { xcp + (size_t)ym * HW, xcp + (size_t)y * HW,
                                xcp + (size_t)yp * HW };
        float ov[4] = {0.f, 0.f, 0.f, 0.f};
        #pragma unroll
        for (int dy = 0; dy < 3; ++dy) {
            const float* rr = rws[dy];
            float  w0 = rr[lx];
            float4 mm = *(const float4*)(rr + px0);
            float  w5 = rr[rx];
            float wvv[6] = { w0, mm.x, mm.y, mm.z, mm.w, w5 };
            #pragma unroll
            for (int j = 0; j < 4; ++j) {
                #pragma unroll
                for (int dx = 0; dx < 3; ++dx)
                    ov[j] = fmaf(wvv[j + dx], sgv[dy * 3 + dx][j], ov[j]);
            }
        }
        float4 o4 = { ov[0], ov[1], ov[2], ov[3] };
        *(float4*)(on + (size_t)c * PLANE + (size_t)y * HW + px0) = o4;
    }
}

extern "C" void kernel_launch(void* const* d_in, const int* in_sizes, int n_in,
                              void* d_out, int out_size, void* d_ws, size_t ws_size,
                              hipStream_t stream) {
    const float* x     = (const float*)d_in[0];
    const float* w     = (const float*)d_in[1];
    const float* gamma = (const float*)d_in[2];
    const float* beta  = (const float*)d_in[3];
    const float* rmean = (const float*)d_in[4];
    const float* rvar  = (const float*)d_in[5];
    float* out   = (float*)d_out;
    float* sigma = (float*)d_ws;                 // 8*18*16384*4 = 9.44 MB

    // scratch in d_out (pool fully overwrites d_out last, after conv reads):
    //   xc (NHWC bf16): 8*128*128*256*2 = 67.1 MB at offset 0
    //   wB: 147 KB at byte offset 80 MB
    unsigned short* xcb = (unsigned short*)d_out;
    unsigned short* wB  = (unsigned short*)((char*)d_out + (size_t)80 * 1024 * 1024);

    pasa_wprep<<<dim3(288), dim3(256), 0, stream>>>(w, wB);
    pasa_cvt<<<dim3(4096), dim3(256), 0, stream>>>(x, xcb);
    pasa_conv_mfma<<<dim3(1024), dim3(256), 0, stream>>>(
        xcb, wB, gamma, beta, rmean, rvar, sigma);
    pasa_pool<<<dim3(2048), dim3(256), 0, stream>>>(x, sigma, out);
}